// Round 11
// baseline (441.323 us; speedup 1.0000x reference)
//
#include <hip/hip_runtime.h>
#include <hip/hip_cooperative_groups.h>

namespace cg = cooperative_groups;

#define N_NODES 16384
#define N_EDGES 262144
#define F_IN    128
#define DIM     64
#define N_CLS   40
#define KT      16
#define NBLK    512                // 2 blocks/CU needed; >=4 available -> 2x slack
#define NPN     8                  // nodes per wave (512*4 waves * 8 = 16384)
#define MOUT    (KT * (DIM + 1))   // 1040 moment outputs
#define SLOTS   64                 // max degree slots (Poisson(16): P(>64) ~ 1e-15)
#define EPSF    1e-8f

__device__ __forceinline__ float rlane(float v, int k) {
    return __int_as_float(__builtin_amdgcn_readlane(__float_as_int(v), k));
}
__device__ __forceinline__ int rlane_i(int v, int k) {
    return __builtin_amdgcn_readlane(v, k);
}
__device__ __forceinline__ unsigned short f2bf(float f) {
    unsigned int u = __float_as_uint(f);
    return (unsigned short)((u + 0x7FFFu + ((u >> 16) & 1u)) >> 16);
}
__device__ __forceinline__ float bf2f(unsigned short h) {
    return __uint_as_float(((unsigned int)h) << 16);
}

// single-pass gather (d <= SLOTS): wave sums bf16 rows of node's neighbors
__device__ __forceinline__ float gather_node(const int* __restrict__ ssrc,
                                             const unsigned short* __restrict__ p16,
                                             int node, int d, int lane) {
    const int eid = (lane < d) ? ssrc[(node << 6) + lane] : 0;
    float acc = 0.f;
    int t = 0;
    for (; t + 8 <= d; t += 8) {
        const int s_0 = rlane_i(eid, t + 0), s_1 = rlane_i(eid, t + 1);
        const int s_2 = rlane_i(eid, t + 2), s_3 = rlane_i(eid, t + 3);
        const int s_4 = rlane_i(eid, t + 4), s_5 = rlane_i(eid, t + 5);
        const int s_6 = rlane_i(eid, t + 6), s_7 = rlane_i(eid, t + 7);
        const unsigned short u0 = p16[(size_t)s_0 * DIM + lane];
        const unsigned short u1 = p16[(size_t)s_1 * DIM + lane];
        const unsigned short u2 = p16[(size_t)s_2 * DIM + lane];
        const unsigned short u3 = p16[(size_t)s_3 * DIM + lane];
        const unsigned short u4 = p16[(size_t)s_4 * DIM + lane];
        const unsigned short u5 = p16[(size_t)s_5 * DIM + lane];
        const unsigned short u6 = p16[(size_t)s_6 * DIM + lane];
        const unsigned short u7 = p16[(size_t)s_7 * DIM + lane];
        acc += ((bf2f(u0) + bf2f(u1)) + (bf2f(u2) + bf2f(u3))) +
               ((bf2f(u4) + bf2f(u5)) + (bf2f(u6) + bf2f(u7)));
    }
    for (; t < d; ++t) {
        const int s = rlane_i(eid, t);
        acc += bf2f(p16[(size_t)s * DIM + lane]);
    }
    return acc;
}

__global__ __launch_bounds__(256, 2) void k_mega(
    const float* __restrict__ x, const int* __restrict__ src, const int* __restrict__ dst,
    const float* __restrict__ W1l, const float* __restrict__ b1, const float* __restrict__ W1r,
    const float* __restrict__ W2l, const float* __restrict__ b2, const float* __restrict__ W2r,
    const float* __restrict__ aux, const float* __restrict__ Wc, const float* __restrict__ bc,
    float* __restrict__ out,
    unsigned short* __restrict__ p1, float* __restrict__ r1,
    unsigned short* __restrict__ p2, float* __restrict__ r2,
    int* __restrict__ deg, int* __restrict__ ssrc,
    float* __restrict__ Mpart, float* __restrict__ Mm)
{
    cg::grid_group grid = cg::this_grid();
    __shared__ __align__(16) float smem[8192];   // 32 KB, re-purposed per phase
    const int tid = threadIdx.x, lane = tid & 63, w = tid >> 6;
    const int bid = blockIdx.x;
    const int wave = bid * 4 + w;                // 0..2047

    // ================= Phase 0: CSR build + proj1 (two-pass W staging) ==========
    {   // build: grid-stride over edges (deg pre-zeroed by the stream memset)
        for (int e = bid * 256 + tid; e < N_EDGES; e += NBLK * 256) {
            const int d = dst[e];
            const int pos = atomicAdd(&deg[d], 1);
            if (pos < SLOTS) ssrc[(d << 6) + pos] = src[e];
        }
    }
    {   // proj1: wave owns 8 rows; stage W1l, compute p1; stage W1r, compute r1
        for (int i = tid; i < F_IN * DIM / 4; i += 256)
            ((float4*)smem)[i] = ((const float4*)W1l)[i];
        const int row0 = wave * NPN;
        float xa[NPN], xb[NPN];
#pragma unroll
        for (int j = 0; j < NPN; ++j) {
            xa[j] = x[(size_t)(row0 + j) * F_IN + lane];
            xb[j] = x[(size_t)(row0 + j) * F_IN + 64 + lane];
        }
        __syncthreads();
        {
            float acc[NPN];
#pragma unroll
            for (int j = 0; j < NPN; ++j) acc[j] = 0.f;
#pragma unroll 8
            for (int k = 0; k < 64; ++k) {
                const float wl = smem[k * DIM + lane];
#pragma unroll
                for (int j = 0; j < NPN; ++j) acc[j] = fmaf(rlane(xa[j], k), wl, acc[j]);
            }
#pragma unroll 8
            for (int k = 0; k < 64; ++k) {
                const float wl = smem[(64 + k) * DIM + lane];
#pragma unroll
                for (int j = 0; j < NPN; ++j) acc[j] = fmaf(rlane(xb[j], k), wl, acc[j]);
            }
#pragma unroll
            for (int j = 0; j < NPN; ++j) p1[(size_t)(row0 + j) * DIM + lane] = f2bf(acc[j]);
        }
        __syncthreads();
        for (int i = tid; i < F_IN * DIM / 4; i += 256)
            ((float4*)smem)[i] = ((const float4*)W1r)[i];
        __syncthreads();
        {
            float acc[NPN];
#pragma unroll
            for (int j = 0; j < NPN; ++j) acc[j] = 0.f;
#pragma unroll 8
            for (int k = 0; k < 64; ++k) {
                const float wl = smem[k * DIM + lane];
#pragma unroll
                for (int j = 0; j < NPN; ++j) acc[j] = fmaf(rlane(xa[j], k), wl, acc[j]);
            }
#pragma unroll 8
            for (int k = 0; k < 64; ++k) {
                const float wl = smem[(64 + k) * DIM + lane];
#pragma unroll
                for (int j = 0; j < NPN; ++j) acc[j] = fmaf(rlane(xb[j], k), wl, acc[j]);
            }
#pragma unroll
            for (int j = 0; j < NPN; ++j) r1[(size_t)(row0 + j) * DIM + lane] = acc[j];
        }
    }
    grid.sync();

    // ================= Phase 1: gather1 + proj2 (h1 stays in registers) =========
    {
        for (int i = tid; i < DIM * DIM / 4; i += 256) {
            ((float4*)smem)[i]          = ((const float4*)W2l)[i];
            ((float4*)(smem + 4096))[i] = ((const float4*)W2r)[i];
        }
        const float bb = b1[lane];
        const int node0 = wave * NPN;
        float h1v[NPN];
#pragma unroll
        for (int jj = 0; jj < NPN; ++jj) {
            const int node = node0 + jj;
            const int d = min(deg[node], SLOTS);
            const float acc = gather_node(ssrc, p1, node, d, lane);
            const float val = acc / fmaxf((float)d, 1.f) + bb + r1[(size_t)node * DIM + lane];
            h1v[jj] = fmaxf(val, 0.f);
        }
        __syncthreads();
        float accl[NPN], accr[NPN];
#pragma unroll
        for (int j = 0; j < NPN; ++j) { accl[j] = 0.f; accr[j] = 0.f; }
#pragma unroll 8
        for (int k = 0; k < DIM; ++k) {
            const float wl = smem[k * DIM + lane];
            const float wr = smem[4096 + k * DIM + lane];
#pragma unroll
            for (int jj = 0; jj < NPN; ++jj) {
                const float hk = rlane(h1v[jj], k);
                accl[jj] = fmaf(hk, wl, accl[jj]);
                accr[jj] = fmaf(hk, wr, accr[jj]);
            }
        }
#pragma unroll
        for (int jj = 0; jj < NPN; ++jj) {
            p2[(size_t)(node0 + jj) * DIM + lane] = f2bf(accl[jj]);
            r2[(size_t)(node0 + jj) * DIM + lane] = accr[jj];
        }
    }
    grid.sync();

    // ================= Phase 2: gather2 + score + moments (h2/score in regs) ====
    float hv2[NPN], sc[NPN];
    {
        const float bb = b2[lane];
        const float av = aux[lane];
        float an2 = av * av;
#pragma unroll
        for (int off = 32; off >= 1; off >>= 1) an2 += __shfl_xor(an2, off);
        const float anorm = fmaxf(sqrtf(an2), EPSF);

        float accM[KT], accm[KT];
#pragma unroll
        for (int k = 0; k < KT; ++k) { accM[k] = 0.f; accm[k] = 0.f; }

        const int node0 = wave * NPN;
#pragma unroll
        for (int jj = 0; jj < NPN; ++jj) {
            const int node = node0 + jj;
            const int d = min(deg[node], SLOTS);
            const float acc = gather_node(ssrc, p2, node, d, lane);
            const float hv = acc / fmaxf((float)d, 1.f) + bb + r2[(size_t)node * DIM + lane];
            hv2[jj] = hv;
            float d1 = hv * av, d2 = hv * hv;
#pragma unroll
            for (int off = 32; off >= 1; off >>= 1) {
                d1 += __shfl_xor(d1, off);
                d2 += __shfl_xor(d2, off);
            }
            const float s = d1 / (anorm * fmaxf(sqrtf(d2), EPSF));
            sc[jj] = s;
            float tt = expf(-s * s);
#pragma unroll
            for (int k = 0; k < KT; ++k) {
                accM[k] = fmaf(tt, hv, accM[k]);
                accm[k] += tt;
                tt *= s;
            }
        }

        // block-level moment reduction in LDS, contiguous partial store
        float* sM  = smem;              // KT*DIM = 1024
        float* smm = smem + KT * DIM;   // KT
        __syncthreads();
        if (w == 0) {
#pragma unroll
            for (int k = 0; k < KT; ++k) sM[k * DIM + lane] = accM[k];
            if (lane == 0)
                for (int k = 0; k < KT; ++k) smm[k] = accm[k];
        }
        __syncthreads();
        if (w != 0) {
            for (int k = 0; k < KT; ++k) atomicAdd(&sM[k * DIM + lane], accM[k]);
            if (lane == 0)
                for (int k = 0; k < KT; ++k) atomicAdd(&smm[k], accm[k]);
        }
        __syncthreads();
        float* mp = Mpart + (size_t)bid * MOUT;
        for (int o = tid; o < KT * DIM; o += 256) mp[o] = sM[o];
        if (tid < KT) mp[KT * DIM + tid] = smm[tid];
    }
    grid.sync();

    // ================= Phase 3: reduce 512 partial rows -> Mm ===================
    if (bid < 16) {
        for (int o = tid; o < MOUT; o += 256) {
            float s = 0.f;
            for (int b = bid * 32; b < bid * 32 + 32; ++b)
                s += Mpart[(size_t)b * MOUT + o];
            atomicAdd(&Mm[o], s);   // Mm pre-zeroed by the stream memset; 16-way contention
        }
    }
    grid.sync();

    // ================= Phase 4: z + classifier (h2/score from registers) ========
    {
        float* sWc = smem;          // 5120
        float* sbc = smem + 5120;   // 40
        float* sMo = smem + 5160;   // 1024
        float* smv = smem + 6184;   // 16
        float* sh  = smem + 6200;   // 256
        float* sz  = smem + 6456;   // 256
        for (int i = tid; i < 2 * DIM * N_CLS; i += 256) sWc[i] = Wc[i];
        if (tid < N_CLS) sbc[tid] = bc[tid];
        for (int i = tid; i < KT * DIM; i += 256) sMo[i] = Mm[i];
        if (tid < KT) smv[tid] = Mm[KT * DIM + tid];
        __syncthreads();

        const int node0 = wave * NPN;
#pragma unroll
        for (int jj = 0; jj < NPN; ++jj) {
            const int node = node0 + jj;
            const float s2 = 2.f * sc[jj];
            float c = 1.f, num = 0.f, den = 0.f;
#pragma unroll
            for (int k = 0; k < KT; ++k) {
                num = fmaf(c, sMo[k * DIM + lane], num);
                den = fmaf(c, smv[k], den);
                c *= s2 * (1.0f / (float)(k + 1));
            }
            sz[w * DIM + lane] = num / den;
            sh[w * DIM + lane] = hv2[jj];
            // same-wave LDS write->read; compiler inserts lgkmcnt wait
            if (lane < N_CLS) {
                float a = sbc[lane];
#pragma unroll 8
                for (int k = 0; k < DIM; ++k)
                    a = fmaf(sh[w * DIM + k], sWc[k * N_CLS + lane], a);
#pragma unroll 8
                for (int k = 0; k < DIM; ++k)
                    a = fmaf(sz[w * DIM + k], sWc[(DIM + k) * N_CLS + lane], a);
                out[(size_t)node * N_CLS + lane] = a;
            }
        }
    }
}

extern "C" void kernel_launch(void* const* d_in, const int* in_sizes, int n_in,
                              void* d_out, int out_size, void* d_ws, size_t ws_size,
                              hipStream_t stream) {
    const float* x   = (const float*)d_in[0];
    const int*   ei  = (const int*)d_in[1];
    const float* W1l = (const float*)d_in[2];
    const float* b1  = (const float*)d_in[3];
    const float* W1r = (const float*)d_in[4];
    const float* W2l = (const float*)d_in[5];
    const float* b2  = (const float*)d_in[6];
    const float* W2r = (const float*)d_in[7];
    const float* aux = (const float*)d_in[8];
    const float* Wc  = (const float*)d_in[9];
    const float* bc  = (const float*)d_in[10];
    float*       out = (float*)d_out;

    const int* src = ei;
    const int* dst = ei + N_EDGES;

    float*       W  = (float*)d_ws;
    const size_t ND = (size_t)N_NODES * DIM;
    unsigned short* p1 = (unsigned short*)W;            // bf16 [N, DIM]
    float* r1    = W + ND / 2;                          // f32  [N, DIM]
    unsigned short* p2 = (unsigned short*)(r1 + ND);    // bf16 [N, DIM]
    float* r2    = r1 + ND + ND / 2;                    // f32  [N, DIM]
    int*   deg   = (int*)(r2 + ND);                     // int  [N]
    float* Mm    = (float*)(deg + N_NODES);             // f32  [MOUT]   (contig w/ deg)
    float* Mpart = Mm + MOUT;                           // f32  [NBLK, MOUT]
    int*   ssrc  = (int*)(Mpart + (size_t)NBLK * MOUT); // int  [N, SLOTS]

    // zero deg + Mm in one small memset (contiguous)
    hipMemsetAsync(deg, 0, (N_NODES + MOUT) * sizeof(float), stream);

    void* args[] = {
        (void*)&x, (void*)&src, (void*)&dst,
        (void*)&W1l, (void*)&b1, (void*)&W1r,
        (void*)&W2l, (void*)&b2, (void*)&W2r,
        (void*)&aux, (void*)&Wc, (void*)&bc,
        (void*)&out,
        (void*)&p1, (void*)&r1, (void*)&p2, (void*)&r2,
        (void*)&deg, (void*)&ssrc, (void*)&Mpart, (void*)&Mm,
    };
    hipLaunchCooperativeKernel((void*)k_mega, dim3(NBLK), dim3(256), args, 0, stream);
}

// Round 12
// 296.951 us; speedup vs baseline: 1.4862x; 1.4862x over previous
//
#include <hip/hip_runtime.h>

#define N_NODES 16384
#define N_EDGES 262144
#define F_IN    128
#define DIM     64
#define N_CLS   40
#define KT      16
#define NPART   4096               // gather2 blocks (1 node per wave)
#define NRED    16
#define MOUT    (KT * (DIM + 1))   // 1040 moment outputs
#define SLOTS   64                 // max degree slots (Poisson(16): P(>64) ~ 1e-15)
#define EPSF    1e-8f

__device__ __forceinline__ float rlane(float v, int k) {
    return __int_as_float(__builtin_amdgcn_readlane(__float_as_int(v), k));
}
__device__ __forceinline__ int rlane_i(int v, int k) {
    return __builtin_amdgcn_readlane(v, k);
}
__device__ __forceinline__ unsigned short f2bf(float f) {
    unsigned int u = __float_as_uint(f);
    return (unsigned short)((u + 0x7FFFu + ((u >> 16) & 1u)) >> 16);
}
__device__ __forceinline__ float bf2f(unsigned short h) {
    return __uint_as_float(((unsigned int)h) << 16);
}

// single-pass gather (d <= SLOTS): wave sums bf16 rows of node's neighbors
__device__ __forceinline__ float gather_node(const int* __restrict__ ssrc,
                                             const unsigned short* __restrict__ p16,
                                             int node, int d, int lane) {
    const int eid = (lane < d) ? ssrc[(node << 6) + lane] : 0;
    float acc = 0.f;
    int t = 0;
    for (; t + 8 <= d; t += 8) {
        const int s_0 = rlane_i(eid, t + 0), s_1 = rlane_i(eid, t + 1);
        const int s_2 = rlane_i(eid, t + 2), s_3 = rlane_i(eid, t + 3);
        const int s_4 = rlane_i(eid, t + 4), s_5 = rlane_i(eid, t + 5);
        const int s_6 = rlane_i(eid, t + 6), s_7 = rlane_i(eid, t + 7);
        const unsigned short u0 = p16[(size_t)s_0 * DIM + lane];
        const unsigned short u1 = p16[(size_t)s_1 * DIM + lane];
        const unsigned short u2 = p16[(size_t)s_2 * DIM + lane];
        const unsigned short u3 = p16[(size_t)s_3 * DIM + lane];
        const unsigned short u4 = p16[(size_t)s_4 * DIM + lane];
        const unsigned short u5 = p16[(size_t)s_5 * DIM + lane];
        const unsigned short u6 = p16[(size_t)s_6 * DIM + lane];
        const unsigned short u7 = p16[(size_t)s_7 * DIM + lane];
        acc += ((bf2f(u0) + bf2f(u1)) + (bf2f(u2) + bf2f(u3))) +
               ((bf2f(u4) + bf2f(u5)) + (bf2f(u6) + bf2f(u7)));
    }
    for (; t < d; ++t) {
        const int s = rlane_i(eid, t);
        acc += bf2f(p16[(size_t)s * DIM + lane]);
    }
    return acc;
}

// ---------------- proj1 + edge build: p1(bf16)=X@W1l, r1=X@W1r; bucket edges ----------------
__global__ __launch_bounds__(256) void k_projb(const float* __restrict__ X,
                                               const float* __restrict__ Wl,
                                               const float* __restrict__ Wr,
                                               const int* __restrict__ src,
                                               const int* __restrict__ dst,
                                               int* __restrict__ deg,
                                               int* __restrict__ ssrc,
                                               unsigned short* __restrict__ p16,
                                               float* __restrict__ r) {
    const int tid = threadIdx.x, lane = tid & 63, w = tid >> 6;

    // edge build first (atomics overlap the weight staging of other waves/blocks)
    for (int e = blockIdx.x * 256 + tid; e < N_EDGES; e += 512 * 256) {
        const int d = dst[e];
        const int pos = atomicAdd(&deg[d], 1);
        if (pos < SLOTS) ssrc[(d << 6) + pos] = src[e];
    }

    __shared__ float sWl[F_IN * DIM];
    __shared__ float sWr[F_IN * DIM];
    for (int i = tid; i < F_IN * DIM / 4; i += 256) {
        ((float4*)sWl)[i] = ((const float4*)Wl)[i];
        ((float4*)sWr)[i] = ((const float4*)Wr)[i];
    }
    __syncthreads();

    const int row0 = (blockIdx.x * 4 + w) * 8;
    float xa[8], xb[8];
#pragma unroll
    for (int j = 0; j < 8; ++j) {
        xa[j] = X[(size_t)(row0 + j) * F_IN + lane];
        xb[j] = X[(size_t)(row0 + j) * F_IN + 64 + lane];
    }
    float accl[8] = {0.f, 0.f, 0.f, 0.f, 0.f, 0.f, 0.f, 0.f};
    float accr[8] = {0.f, 0.f, 0.f, 0.f, 0.f, 0.f, 0.f, 0.f};
#pragma unroll 8
    for (int k = 0; k < 64; ++k) {
        const float wl = sWl[k * DIM + lane];
        const float wr = sWr[k * DIM + lane];
#pragma unroll
        for (int j = 0; j < 8; ++j) {
            const float xv = rlane(xa[j], k);
            accl[j] = fmaf(xv, wl, accl[j]);
            accr[j] = fmaf(xv, wr, accr[j]);
        }
    }
#pragma unroll 8
    for (int k = 0; k < 64; ++k) {
        const float wl = sWl[(64 + k) * DIM + lane];
        const float wr = sWr[(64 + k) * DIM + lane];
#pragma unroll
        for (int j = 0; j < 8; ++j) {
            const float xv = rlane(xb[j], k);
            accl[j] = fmaf(xv, wl, accl[j]);
            accr[j] = fmaf(xv, wr, accr[j]);
        }
    }
#pragma unroll
    for (int j = 0; j < 8; ++j) {
        p16[(size_t)(row0 + j) * DIM + lane] = f2bf(accl[j]);
        r[(size_t)(row0 + j) * DIM + lane]   = accr[j];
    }
}

// ---------------- fused gather1 + proj2 (2 nodes/wave, 8192 waves) ----------------
__global__ __launch_bounds__(256) void k_g1p2(const int* __restrict__ ssrc,
                                              const int* __restrict__ deg,
                                              const unsigned short* __restrict__ p1,
                                              const float* __restrict__ r1,
                                              const float* __restrict__ b1,
                                              const float* __restrict__ W2l,
                                              const float* __restrict__ W2r,
                                              unsigned short* __restrict__ p2,
                                              float* __restrict__ r2) {
    __shared__ float sWl[DIM * DIM];
    __shared__ float sWr[DIM * DIM];
    const int tid = threadIdx.x, lane = tid & 63, w = tid >> 6;
    for (int i = tid; i < DIM * DIM / 4; i += 256) {
        ((float4*)sWl)[i] = ((const float4*)W2l)[i];
        ((float4*)sWr)[i] = ((const float4*)W2r)[i];
    }
    __syncthreads();

    const float bb = b1[lane];
    const int node0 = (blockIdx.x * 4 + w) * 2;   // 2 nodes per wave
    float h1v[2];
#pragma unroll
    for (int jj = 0; jj < 2; ++jj) {
        const int node = node0 + jj;
        const int d = min(deg[node], SLOTS);
        const float acc = gather_node(ssrc, p1, node, d, lane);
        const float val = acc / fmaxf((float)d, 1.f) + bb + r1[(size_t)node * DIM + lane];
        h1v[jj] = fmaxf(val, 0.f);
    }
    float accl[2] = {0.f, 0.f};
    float accr[2] = {0.f, 0.f};
#pragma unroll 8
    for (int k = 0; k < DIM; ++k) {
        const float wl = sWl[k * DIM + lane];
        const float wr = sWr[k * DIM + lane];
#pragma unroll
        for (int jj = 0; jj < 2; ++jj) {
            const float hk = rlane(h1v[jj], k);
            accl[jj] = fmaf(hk, wl, accl[jj]);
            accr[jj] = fmaf(hk, wr, accr[jj]);
        }
    }
#pragma unroll
    for (int jj = 0; jj < 2; ++jj) {
        p2[(size_t)(node0 + jj) * DIM + lane] = f2bf(accl[jj]);
        r2[(size_t)(node0 + jj) * DIM + lane] = accr[jj];
    }
}

// ---------------- gather2 + score + moments (1 node/wave, 16384 waves) ----------------
__global__ __launch_bounds__(256) void k_gather2(const int* __restrict__ ssrc,
                                                 const int* __restrict__ deg,
                                                 const unsigned short* __restrict__ p2,
                                                 const float* __restrict__ r2,
                                                 const float* __restrict__ b2,
                                                 const float* __restrict__ aux,
                                                 float* __restrict__ h2,
                                                 float* __restrict__ score,
                                                 float* __restrict__ Mpart) {
    const int lane = threadIdx.x & 63, w = threadIdx.x >> 6;
    const int tid = threadIdx.x;

    const float bb = b2[lane];
    const float av = aux[lane];
    float an2 = av * av;
#pragma unroll
    for (int off = 32; off >= 1; off >>= 1) an2 += __shfl_xor(an2, off);
    const float anorm = fmaxf(sqrtf(an2), EPSF);

    float accM[KT], accm[KT];
#pragma unroll
    for (int k = 0; k < KT; ++k) { accM[k] = 0.f; accm[k] = 0.f; }

    {
        const int node = blockIdx.x * 4 + w;   // 1 node per wave
        const int d = min(deg[node], SLOTS);
        const float acc = gather_node(ssrc, p2, node, d, lane);
        const float hv = acc / fmaxf((float)d, 1.f) + bb + r2[(size_t)node * DIM + lane];
        h2[(size_t)node * DIM + lane] = hv;

        float d1 = hv * av, d2 = hv * hv;
#pragma unroll
        for (int off = 32; off >= 1; off >>= 1) {
            d1 += __shfl_xor(d1, off);
            d2 += __shfl_xor(d2, off);
        }
        const float s = d1 / (anorm * fmaxf(sqrtf(d2), EPSF));
        if (lane == 0) score[node] = s;
        float tt = expf(-s * s);
#pragma unroll
        for (int k = 0; k < KT; ++k) {
            accM[k] = fmaf(tt, hv, accM[k]);
            accm[k] += tt;
            tt *= s;
        }
    }

    // block-level reduction in LDS, then contiguous partial store
    __shared__ float sM[KT][DIM];
    __shared__ float smm[KT];
    __syncthreads();
    if (w == 0) {
#pragma unroll
        for (int k = 0; k < KT; ++k) sM[k][lane] = accM[k];
        if (lane == 0)
            for (int k = 0; k < KT; ++k) smm[k] = accm[k];
    }
    __syncthreads();
    if (w != 0) {
        for (int k = 0; k < KT; ++k) atomicAdd(&sM[k][lane], accM[k]);
        if (lane == 0)
            for (int k = 0; k < KT; ++k) atomicAdd(&smm[k], accm[k]);
    }
    __syncthreads();
    float* mp = Mpart + (size_t)blockIdx.x * MOUT;
    const float* sMf = &sM[0][0];
    for (int o = tid; o < KT * DIM; o += 256) mp[o] = sMf[o];
    if (tid < KT) mp[KT * DIM + tid] = smm[tid];
}

// ---------------- reduce 4096 partial rows -> 16 rows (plain stores) ----------------
__global__ __launch_bounds__(1024) void k_mred(const float* __restrict__ Mpart,
                                               float* __restrict__ Mpart2) {
    const int t = threadIdx.x, B = blockIdx.x;
    float s1 = 0.f, s2 = 0.f;
    for (int b = B * 256; b < B * 256 + 256; ++b) {
        const float* row = Mpart + (size_t)b * MOUT;
        s1 += row[t];
        if (t < MOUT - 1024) s2 += row[1024 + t];
    }
    Mpart2[(size_t)B * MOUT + t] = s1;
    if (t < MOUT - 1024) Mpart2[(size_t)B * MOUT + 1024 + t] = s2;
}

// ---------------- fused z + classifier (reduces the 16 partial rows at load) ----------------
__global__ __launch_bounds__(256) void k_zcls(const float* __restrict__ score,
                                              const float* __restrict__ Mpart2,
                                              const float* __restrict__ h,
                                              const float* __restrict__ Wc,
                                              const float* __restrict__ bc,
                                              float* __restrict__ out) {
    __shared__ float sM[KT * DIM];
    __shared__ float sm[KT];
    __shared__ float sW[2 * DIM * N_CLS];
    __shared__ float sb[N_CLS];
    __shared__ float sh[4][DIM];
    __shared__ float sz[4][DIM];
    const int tid = threadIdx.x;
    for (int idx = tid; idx < KT * DIM; idx += 256) {
        float s = 0.f;
#pragma unroll
        for (int B = 0; B < NRED; ++B) s += Mpart2[(size_t)B * MOUT + idx];
        sM[idx] = s;
    }
    if (tid < KT) {
        float s = 0.f;
#pragma unroll
        for (int B = 0; B < NRED; ++B) s += Mpart2[(size_t)B * MOUT + KT * DIM + tid];
        sm[tid] = s;
    }
    for (int idx = tid; idx < 2 * DIM * N_CLS; idx += 256) sW[idx] = Wc[idx];
    if (tid < N_CLS) sb[tid] = bc[tid];
    __syncthreads();

    const int lane = tid & 63, w = tid >> 6;
    const int gw = blockIdx.x * 4 + w, nw = gridDim.x * 4;
    for (int i = gw; i < N_NODES; i += nw) {
        const float s2 = 2.f * score[i];
        float c = 1.f, num = 0.f, den = 0.f;
#pragma unroll
        for (int k = 0; k < KT; ++k) {
            num = fmaf(c, sM[k * DIM + lane], num);
            den = fmaf(c, sm[k], den);
            c *= s2 * (1.0f / (float)(k + 1));
        }
        sz[w][lane] = num / den;
        sh[w][lane] = h[(size_t)i * DIM + lane];
        if (lane < N_CLS) {
            float acc = sb[lane];
#pragma unroll 8
            for (int k = 0; k < DIM; ++k)
                acc = fmaf(sh[w][k], sW[k * N_CLS + lane], acc);
#pragma unroll 8
            for (int k = 0; k < DIM; ++k)
                acc = fmaf(sz[w][k], sW[(DIM + k) * N_CLS + lane], acc);
            out[(size_t)i * N_CLS + lane] = acc;
        }
    }
}

extern "C" void kernel_launch(void* const* d_in, const int* in_sizes, int n_in,
                              void* d_out, int out_size, void* d_ws, size_t ws_size,
                              hipStream_t stream) {
    const float* x   = (const float*)d_in[0];
    const int*   ei  = (const int*)d_in[1];
    const float* W1l = (const float*)d_in[2];
    const float* b1  = (const float*)d_in[3];
    const float* W1r = (const float*)d_in[4];
    const float* W2l = (const float*)d_in[5];
    const float* b2  = (const float*)d_in[6];
    const float* W2r = (const float*)d_in[7];
    const float* aux = (const float*)d_in[8];
    const float* Wc  = (const float*)d_in[9];
    const float* bc  = (const float*)d_in[10];
    float*       out = (float*)d_out;

    const int* src = ei;
    const int* dst = ei + N_EDGES;

    float*       W  = (float*)d_ws;
    const size_t ND = (size_t)N_NODES * DIM;
    unsigned short* p1 = (unsigned short*)W;            // bf16 [N, DIM]
    float* r1    = W + ND / 2;                          // f32  [N, DIM]
    unsigned short* p2 = (unsigned short*)(r1 + ND);    // bf16 [N, DIM]
    float* r2    = r1 + ND + ND / 2;                    // f32  [N, DIM]
    float* h2    = r2 + ND;                             // f32  [N, DIM]
    float* score = h2 + ND;                             // f32  [N]
    int*   deg   = (int*)(score + N_NODES);             // int  [N]
    float* Mpart = (float*)(deg + N_NODES);             // f32  [NPART, MOUT]
    float* Mpart2= Mpart + (size_t)NPART * MOUT;        // f32  [NRED, MOUT]
    int*   ssrc  = (int*)(Mpart2 + (size_t)NRED * MOUT);// int  [N, SLOTS]

    hipMemsetAsync(deg, 0, N_NODES * sizeof(int), stream);
    k_projb<<<512, 256, 0, stream>>>(x, W1l, W1r, src, dst, deg, ssrc, p1, r1);
    k_g1p2<<<N_NODES / 8, 256, 0, stream>>>(ssrc, deg, p1, r1, b1, W2l, W2r, p2, r2);
    k_gather2<<<NPART, 256, 0, stream>>>(ssrc, deg, p2, r2, b2, aux, h2, score, Mpart);
    k_mred<<<NRED, 1024, 0, stream>>>(Mpart, Mpart2);
    k_zcls<<<512, 256, 0, stream>>>(score, Mpart2, h2, Wc, bc, out);
}

// Round 13
// 199.025 us; speedup vs baseline: 2.2174x; 1.4920x over previous
//
#include <hip/hip_runtime.h>

#define N_NODES 16384
#define N_EDGES 262144
#define F_IN    128
#define DIM     64
#define N_CLS   40
#define KT      16
#define NPART   1024               // gather2 blocks (grid-stride, 4 nodes/wave, 16/block)
#define NRED    16
#define MOUT    (KT * (DIM + 1))   // 1040 moment outputs
#define SLOTS   64                 // max degree slots (Poisson(16): P(>64) ~ 1e-15)
#define EPSF    1e-8f

__device__ __forceinline__ float rlane(float v, int k) {
    return __int_as_float(__builtin_amdgcn_readlane(__float_as_int(v), k));
}
__device__ __forceinline__ int rlane_i(int v, int k) {
    return __builtin_amdgcn_readlane(v, k);
}
__device__ __forceinline__ unsigned short f2bf(float f) {
    unsigned int u = __float_as_uint(f);
    return (unsigned short)((u + 0x7FFFu + ((u >> 16) & 1u)) >> 16);
}
__device__ __forceinline__ float bf2f(unsigned short h) {
    return __uint_as_float(((unsigned int)h) << 16);
}

// single-pass gather (d <= SLOTS): wave sums bf16 rows of node's neighbors
__device__ __forceinline__ float gather_node(const int* __restrict__ ssrc,
                                             const unsigned short* __restrict__ p16,
                                             int node, int d, int lane) {
    const int eid = (lane < d) ? ssrc[(node << 6) + lane] : 0;
    float acc = 0.f;
    int t = 0;
    for (; t + 8 <= d; t += 8) {
        const int s_0 = rlane_i(eid, t + 0), s_1 = rlane_i(eid, t + 1);
        const int s_2 = rlane_i(eid, t + 2), s_3 = rlane_i(eid, t + 3);
        const int s_4 = rlane_i(eid, t + 4), s_5 = rlane_i(eid, t + 5);
        const int s_6 = rlane_i(eid, t + 6), s_7 = rlane_i(eid, t + 7);
        const unsigned short u0 = p16[(size_t)s_0 * DIM + lane];
        const unsigned short u1 = p16[(size_t)s_1 * DIM + lane];
        const unsigned short u2 = p16[(size_t)s_2 * DIM + lane];
        const unsigned short u3 = p16[(size_t)s_3 * DIM + lane];
        const unsigned short u4 = p16[(size_t)s_4 * DIM + lane];
        const unsigned short u5 = p16[(size_t)s_5 * DIM + lane];
        const unsigned short u6 = p16[(size_t)s_6 * DIM + lane];
        const unsigned short u7 = p16[(size_t)s_7 * DIM + lane];
        acc += ((bf2f(u0) + bf2f(u1)) + (bf2f(u2) + bf2f(u3))) +
               ((bf2f(u4) + bf2f(u5)) + (bf2f(u6) + bf2f(u7)));
    }
    for (; t < d; ++t) {
        const int s = rlane_i(eid, t);
        acc += bf2f(p16[(size_t)s * DIM + lane]);
    }
    return acc;
}

// ---------------- proj1 + edge build: p1(bf16)=X@W1l, r1=X@W1r; bucket edges ----------------
__global__ __launch_bounds__(256) void k_projb(const float* __restrict__ X,
                                               const float* __restrict__ Wl,
                                               const float* __restrict__ Wr,
                                               const int* __restrict__ src,
                                               const int* __restrict__ dst,
                                               int* __restrict__ deg,
                                               int* __restrict__ ssrc,
                                               unsigned short* __restrict__ p16,
                                               float* __restrict__ r) {
    const int tid = threadIdx.x, lane = tid & 63, w = tid >> 6;

    // edge build first (atomics overlap weight staging of other blocks)
    for (int e = blockIdx.x * 256 + tid; e < N_EDGES; e += 512 * 256) {
        const int d = dst[e];
        const int pos = atomicAdd(&deg[d], 1);
        if (pos < SLOTS) ssrc[(d << 6) + pos] = src[e];
    }

    __shared__ float sWl[F_IN * DIM];
    __shared__ float sWr[F_IN * DIM];
    for (int i = tid; i < F_IN * DIM / 4; i += 256) {
        ((float4*)sWl)[i] = ((const float4*)Wl)[i];
        ((float4*)sWr)[i] = ((const float4*)Wr)[i];
    }
    __syncthreads();

    const int row0 = (blockIdx.x * 4 + w) * 8;
    float xa[8], xb[8];
#pragma unroll
    for (int j = 0; j < 8; ++j) {
        xa[j] = X[(size_t)(row0 + j) * F_IN + lane];
        xb[j] = X[(size_t)(row0 + j) * F_IN + 64 + lane];
    }
    float accl[8] = {0.f, 0.f, 0.f, 0.f, 0.f, 0.f, 0.f, 0.f};
    float accr[8] = {0.f, 0.f, 0.f, 0.f, 0.f, 0.f, 0.f, 0.f};
#pragma unroll 8
    for (int k = 0; k < 64; ++k) {
        const float wl = sWl[k * DIM + lane];
        const float wr = sWr[k * DIM + lane];
#pragma unroll
        for (int j = 0; j < 8; ++j) {
            const float xv = rlane(xa[j], k);
            accl[j] = fmaf(xv, wl, accl[j]);
            accr[j] = fmaf(xv, wr, accr[j]);
        }
    }
#pragma unroll 8
    for (int k = 0; k < 64; ++k) {
        const float wl = sWl[(64 + k) * DIM + lane];
        const float wr = sWr[(64 + k) * DIM + lane];
#pragma unroll
        for (int j = 0; j < 8; ++j) {
            const float xv = rlane(xb[j], k);
            accl[j] = fmaf(xv, wl, accl[j]);
            accr[j] = fmaf(xv, wr, accr[j]);
        }
    }
#pragma unroll
    for (int j = 0; j < 8; ++j) {
        p16[(size_t)(row0 + j) * DIM + lane] = f2bf(accl[j]);
        r[(size_t)(row0 + j) * DIM + lane]   = accr[j];
    }
}

// ---------------- fused gather1 + proj2 (4 nodes/wave, 16 nodes/block) ----------------
__global__ __launch_bounds__(256) void k_g1p2(const int* __restrict__ ssrc,
                                              const int* __restrict__ deg,
                                              const unsigned short* __restrict__ p1,
                                              const float* __restrict__ r1,
                                              const float* __restrict__ b1,
                                              const float* __restrict__ W2l,
                                              const float* __restrict__ W2r,
                                              unsigned short* __restrict__ p2,
                                              float* __restrict__ r2) {
    __shared__ float sWl[DIM * DIM];
    __shared__ float sWr[DIM * DIM];
    const int tid = threadIdx.x, lane = tid & 63, w = tid >> 6;
    for (int i = tid; i < DIM * DIM / 4; i += 256) {
        ((float4*)sWl)[i] = ((const float4*)W2l)[i];
        ((float4*)sWr)[i] = ((const float4*)W2r)[i];
    }
    __syncthreads();

    const float bb = b1[lane];
    const int node0 = (blockIdx.x * 4 + w) * 4;   // 4 nodes per wave
    float h1v[4];
#pragma unroll
    for (int jj = 0; jj < 4; ++jj) {
        const int node = node0 + jj;
        const int d = min(deg[node], SLOTS);
        const float acc = gather_node(ssrc, p1, node, d, lane);
        const float val = acc / fmaxf((float)d, 1.f) + bb + r1[(size_t)node * DIM + lane];
        h1v[jj] = fmaxf(val, 0.f);
    }
    float accl[4] = {0.f, 0.f, 0.f, 0.f};
    float accr[4] = {0.f, 0.f, 0.f, 0.f};
#pragma unroll 8
    for (int k = 0; k < DIM; ++k) {
        const float wl = sWl[k * DIM + lane];
        const float wr = sWr[k * DIM + lane];
#pragma unroll
        for (int jj = 0; jj < 4; ++jj) {
            const float hk = rlane(h1v[jj], k);
            accl[jj] = fmaf(hk, wl, accl[jj]);
            accr[jj] = fmaf(hk, wr, accr[jj]);
        }
    }
#pragma unroll
    for (int jj = 0; jj < 4; ++jj) {
        p2[(size_t)(node0 + jj) * DIM + lane] = f2bf(accl[jj]);
        r2[(size_t)(node0 + jj) * DIM + lane] = accr[jj];
    }
}

// ---------------- gather2 + score + moments (grid-stride 4 nodes/wave) ----------------
__global__ __launch_bounds__(256) void k_gather2(const int* __restrict__ ssrc,
                                                 const int* __restrict__ deg,
                                                 const unsigned short* __restrict__ p2,
                                                 const float* __restrict__ r2,
                                                 const float* __restrict__ b2,
                                                 const float* __restrict__ aux,
                                                 float* __restrict__ h2,
                                                 float* __restrict__ score,
                                                 float* __restrict__ Mpart) {
    const int lane = threadIdx.x & 63, w = threadIdx.x >> 6;
    const int tid = threadIdx.x;

    const float bb = b2[lane];
    const float av = aux[lane];
    float an2 = av * av;
#pragma unroll
    for (int off = 32; off >= 1; off >>= 1) an2 += __shfl_xor(an2, off);
    const float anorm = fmaxf(sqrtf(an2), EPSF);

    float accM[KT], accm[KT];
#pragma unroll
    for (int k = 0; k < KT; ++k) { accM[k] = 0.f; accm[k] = 0.f; }

    const int nw = gridDim.x * 4;  // grid must be NPART blocks
    for (int node = blockIdx.x * 4 + w; node < N_NODES; node += nw) {
        const int d = min(deg[node], SLOTS);
        const float acc = gather_node(ssrc, p2, node, d, lane);
        const float hv = acc / fmaxf((float)d, 1.f) + bb + r2[(size_t)node * DIM + lane];
        h2[(size_t)node * DIM + lane] = hv;

        float d1 = hv * av, d2 = hv * hv;
#pragma unroll
        for (int off = 32; off >= 1; off >>= 1) {
            d1 += __shfl_xor(d1, off);
            d2 += __shfl_xor(d2, off);
        }
        const float s = d1 / (anorm * fmaxf(sqrtf(d2), EPSF));
        if (lane == 0) score[node] = s;
        float tt = expf(-s * s);
#pragma unroll
        for (int k = 0; k < KT; ++k) {
            accM[k] = fmaf(tt, hv, accM[k]);
            accm[k] += tt;
            tt *= s;
        }
    }

    __shared__ float sM[KT][DIM];
    __shared__ float smm[KT];
    __syncthreads();
    if (w == 0) {
#pragma unroll
        for (int k = 0; k < KT; ++k) sM[k][lane] = accM[k];
        if (lane == 0)
            for (int k = 0; k < KT; ++k) smm[k] = accm[k];
    }
    __syncthreads();
    if (w != 0) {
        for (int k = 0; k < KT; ++k) atomicAdd(&sM[k][lane], accM[k]);
        if (lane == 0)
            for (int k = 0; k < KT; ++k) atomicAdd(&smm[k], accm[k]);
    }
    __syncthreads();
    float* mp = Mpart + (size_t)blockIdx.x * MOUT;
    const float* sMf = &sM[0][0];
    for (int o = tid; o < KT * DIM; o += 256) mp[o] = sMf[o];
    if (tid < KT) mp[KT * DIM + tid] = smm[tid];
}

// ---------------- reduce 1024 partial rows -> 16 rows (plain stores) ----------------
__global__ __launch_bounds__(1024) void k_mred(const float* __restrict__ Mpart,
                                               float* __restrict__ Mpart2) {
    const int t = threadIdx.x, B = blockIdx.x;
    float s1 = 0.f, s2 = 0.f;
    for (int b = B * 64; b < B * 64 + 64; ++b) {
        const float* row = Mpart + (size_t)b * MOUT;
        s1 += row[t];
        if (t < MOUT - 1024) s2 += row[1024 + t];
    }
    Mpart2[(size_t)B * MOUT + t] = s1;
    if (t < MOUT - 1024) Mpart2[(size_t)B * MOUT + 1024 + t] = s2;
}

// ---------------- fused z + classifier (reduces the 16 partial rows at load) ----------------
__global__ __launch_bounds__(256) void k_zcls(const float* __restrict__ score,
                                              const float* __restrict__ Mpart2,
                                              const float* __restrict__ h,
                                              const float* __restrict__ Wc,
                                              const float* __restrict__ bc,
                                              float* __restrict__ out) {
    __shared__ float sM[KT * DIM];
    __shared__ float sm[KT];
    __shared__ float sW[2 * DIM * N_CLS];
    __shared__ float sb[N_CLS];
    __shared__ float sh[4][DIM];
    __shared__ float sz[4][DIM];
    const int tid = threadIdx.x;
    for (int idx = tid; idx < KT * DIM; idx += 256) {
        float s = 0.f;
#pragma unroll
        for (int B = 0; B < NRED; ++B) s += Mpart2[(size_t)B * MOUT + idx];
        sM[idx] = s;
    }
    if (tid < KT) {
        float s = 0.f;
#pragma unroll
        for (int B = 0; B < NRED; ++B) s += Mpart2[(size_t)B * MOUT + KT * DIM + tid];
        sm[tid] = s;
    }
    for (int idx = tid; idx < 2 * DIM * N_CLS; idx += 256) sW[idx] = Wc[idx];
    if (tid < N_CLS) sb[tid] = bc[tid];
    __syncthreads();

    const int lane = tid & 63, w = tid >> 6;
    const int gw = blockIdx.x * 4 + w, nw = gridDim.x * 4;
    for (int i = gw; i < N_NODES; i += nw) {
        const float s2 = 2.f * score[i];
        float c = 1.f, num = 0.f, den = 0.f;
#pragma unroll
        for (int k = 0; k < KT; ++k) {
            num = fmaf(c, sM[k * DIM + lane], num);
            den = fmaf(c, sm[k], den);
            c *= s2 * (1.0f / (float)(k + 1));
        }
        sz[w][lane] = num / den;
        sh[w][lane] = h[(size_t)i * DIM + lane];
        if (lane < N_CLS) {
            float acc = sb[lane];
#pragma unroll 8
            for (int k = 0; k < DIM; ++k)
                acc = fmaf(sh[w][k], sW[k * N_CLS + lane], acc);
#pragma unroll 8
            for (int k = 0; k < DIM; ++k)
                acc = fmaf(sz[w][k], sW[(DIM + k) * N_CLS + lane], acc);
            out[(size_t)i * N_CLS + lane] = acc;
        }
    }
}

extern "C" void kernel_launch(void* const* d_in, const int* in_sizes, int n_in,
                              void* d_out, int out_size, void* d_ws, size_t ws_size,
                              hipStream_t stream) {
    const float* x   = (const float*)d_in[0];
    const int*   ei  = (const int*)d_in[1];
    const float* W1l = (const float*)d_in[2];
    const float* b1  = (const float*)d_in[3];
    const float* W1r = (const float*)d_in[4];
    const float* W2l = (const float*)d_in[5];
    const float* b2  = (const float*)d_in[6];
    const float* W2r = (const float*)d_in[7];
    const float* aux = (const float*)d_in[8];
    const float* Wc  = (const float*)d_in[9];
    const float* bc  = (const float*)d_in[10];
    float*       out = (float*)d_out;

    const int* src = ei;
    const int* dst = ei + N_EDGES;

    float*       W  = (float*)d_ws;
    const size_t ND = (size_t)N_NODES * DIM;
    unsigned short* p1 = (unsigned short*)W;            // bf16 [N, DIM]
    float* r1    = W + ND / 2;                          // f32  [N, DIM]
    unsigned short* p2 = (unsigned short*)(r1 + ND);    // bf16 [N, DIM]
    float* r2    = r1 + ND + ND / 2;                    // f32  [N, DIM]
    float* h2    = r2 + ND;                             // f32  [N, DIM]
    float* score = h2 + ND;                             // f32  [N]
    int*   deg   = (int*)(score + N_NODES);             // int  [N]
    float* Mpart = (float*)(deg + N_NODES);             // f32  [NPART, MOUT]
    float* Mpart2= Mpart + (size_t)NPART * MOUT;        // f32  [NRED, MOUT]
    int*   ssrc  = (int*)(Mpart2 + (size_t)NRED * MOUT);// int  [N, SLOTS]

    hipMemsetAsync(deg, 0, N_NODES * sizeof(int), stream);
    k_projb<<<512, 256, 0, stream>>>(x, W1l, W1r, src, dst, deg, ssrc, p1, r1);
    k_g1p2<<<N_NODES / 16, 256, 0, stream>>>(ssrc, deg, p1, r1, b1, W2l, W2r, p2, r2);
    k_gather2<<<NPART, 256, 0, stream>>>(ssrc, deg, p2, r2, b2, aux, h2, score, Mpart);
    k_mred<<<NRED, 1024, 0, stream>>>(Mpart, Mpart2);
    k_zcls<<<512, 256, 0, stream>>>(score, Mpart2, h2, Wc, bc, out);
}